// Round 7
// baseline (1889.223 us; speedup 1.0000x reference)
//
#include <hip/hip_runtime.h>

typedef float f32x4 __attribute__((ext_vector_type(4)));
typedef __bf16 bf16x8 __attribute__((ext_vector_type(8)));

#define NROWS 16384   // B*S
#define SEQ   4096
#define EMBD  512
#define MLPD  2048

__device__ inline float gelu_tanh(float x) {
    float t = 0.7978845608028654f * (x + 0.044715f * x * x * x);
    float e = __expf(2.f * t);
    float th = 1.f - 2.f / (1.f + e);
    return 0.5f * x * (1.f + th);
}

// direct global->LDS 16B DMA; LDS dest must be linear in lane order
#define GLOAD16(gp, lp)                                                        \
    __builtin_amdgcn_global_load_lds(                                          \
        (const __attribute__((address_space(1))) void*)(gp),                   \
        (__attribute__((address_space(3))) void*)(lp), 16, 0, 0)

// ---------------- positional table: pos[s][512] ----------------
__global__ void pos_kernel(float* __restrict__ pos) {
    int i = blockIdx.x * 256 + threadIdx.x;        // 4096*256
    int s = i >> 8, j = i & 255;
    float div = __expf((float)j * (-2.f * 9.210340371976184f / 512.f));
    float a = (float)s * div;
    pos[(size_t)s * 512 + 2 * j]     = sinf(a);
    pos[(size_t)s * 512 + 2 * j + 1] = cosf(a);
}

// ---------------- embedding gather + pos add ----------------
__global__ void embed_kernel(const int* __restrict__ tokens,
                             const float* __restrict__ embed,
                             const float* __restrict__ pos,
                             float* __restrict__ x) {
    int row = blockIdx.x;            // 16384
    int t = threadIdx.x;             // 128
    int s = row & (SEQ - 1);
    int tok = tokens[row];
    f32x4 e = *(const f32x4*)(embed + (size_t)tok * 512 + t * 4);
    f32x4 p = *(const f32x4*)(pos + (size_t)s * 512 + t * 4);
    e += p;
    *(f32x4*)(x + (size_t)row * 512 + t * 4) = e;
}

// ---------------- transpose fp32 [K][N] -> bf16 [N][K], batched over z ----------------
__global__ void transpose_bf16(const float* __restrict__ in, __bf16* __restrict__ out,
                               int K, int N, size_t in_lstride, size_t out_lstride) {
    __shared__ float tile[32][33];
    in  += (size_t)blockIdx.z * in_lstride;
    out += (size_t)blockIdx.z * out_lstride;
    int n0 = blockIdx.x * 32, k0 = blockIdx.y * 32;
    int tx = threadIdx.x, ty = threadIdx.y;   // 32 x 8
    #pragma unroll
    for (int i = 0; i < 32; i += 8)
        tile[ty + i][tx] = in[(size_t)(k0 + ty + i) * N + n0 + tx];
    __syncthreads();
    #pragma unroll
    for (int i = 0; i < 32; i += 8)
        out[(size_t)(n0 + ty + i) * K + k0 + tx] = (__bf16)tile[tx][ty + i];
}

// ---------------- LayerNorm (one wave per 512-row) ----------------
template<int OUTBF>
__global__ __launch_bounds__(256) void ln_kernel(
    const float* __restrict__ x, const float* __restrict__ gamma,
    const float* __restrict__ beta, __bf16* __restrict__ outb,
    float* __restrict__ outf) {
    int lane = threadIdx.x & 63;
    size_t row = (size_t)blockIdx.x * 4 + (threadIdx.x >> 6);
    const float* xr = x + row * 512 + lane * 8;
    f32x4 v0 = *(const f32x4*)xr;
    f32x4 v1 = *(const f32x4*)(xr + 4);
    float sum = (v0[0] + v0[1]) + (v0[2] + v0[3]) + (v1[0] + v1[1]) + (v1[2] + v1[3]);
    #pragma unroll
    for (int off = 32; off; off >>= 1) sum += __shfl_xor(sum, off);
    float mu = sum * (1.f / 512.f);
    float vs = 0.f;
    #pragma unroll
    for (int j = 0; j < 4; j++) {
        float d0 = v0[j] - mu; vs += d0 * d0;
        float d1 = v1[j] - mu; vs += d1 * d1;
    }
    #pragma unroll
    for (int off = 32; off; off >>= 1) vs += __shfl_xor(vs, off);
    float inv = rsqrtf(vs * (1.f / 512.f) + 1e-6f);
    const float* gp = gamma + lane * 8;
    const float* bp = beta + lane * 8;
    f32x4 g0 = *(const f32x4*)gp, g1 = *(const f32x4*)(gp + 4);
    f32x4 bb0 = *(const f32x4*)bp, bb1 = *(const f32x4*)(bp + 4);
    float o[8];
    #pragma unroll
    for (int j = 0; j < 4; j++) {
        o[j]     = (v0[j] - mu) * inv * g0[j] + bb0[j];
        o[4 + j] = (v1[j] - mu) * inv * g1[j] + bb1[j];
    }
    if (OUTBF) {
        bf16x8 ov;
        #pragma unroll
        for (int j = 0; j < 8; j++) ov[j] = (__bf16)o[j];
        *(bf16x8*)(outb + row * 512 + lane * 8) = ov;
    } else {
        f32x4 o0 = {o[0], o[1], o[2], o[3]};
        f32x4 o1 = {o[4], o[5], o[6], o[7]};
        *(f32x4*)(outf + row * 512 + lane * 8) = o0;
        *(f32x4*)(outf + row * 512 + lane * 8 + 4) = o1;
    }
}

// ---------------- MFMA GEMM: C[M,N] = A[M,K](bf16) @ BT[N,K](bf16) ----------------
// 8-phase deep-pipelined 256x128 tile (m201-style schedule, adapted):
//   512 threads / 8 waves (4M x 2N), per-wave 64x64 output, BK=64 in 2 k-halves.
//   LDS 96 KB: 2 ktile-dbuf x 2 khalf x (A 256x32 + B 128x32) bf16.
//   Per ktile 4 phases, each: {ds_read frags; issue one half-tile stage
//   (A=2 / B=1 gload_lds); [counted vmcnt]; barrier; lgkmcnt(0); setprio(1);
//   8 MFMA; setprio(0); barrier}.
//   vmcnt(3) ONLY at ph1 (validates this ktile's k-hi) and ph3 (validates
//   next ktile's k-lo); never 0 mid-loop. In-flight queue entering ktile j:
//   [Ajlo2,Bjlo1,Ajhi2,Bjhi1]; ph0 stages A(j+1)lo, ph1 B(j+1)lo -> vmcnt(3)
//   drains Ajhi+Bjhi; ph2 stages A(j+1)hi, ph3 B(j+1)hi -> vmcnt(3) drains
//   A(j+1)lo+B(j+1)lo. Tail ktile: vmcnt(0) at ph1.
//   Swizzle: per 64B khalf-row 4 chunks of 16B, chunk ^= (row>>1)&3 (proven
//   0-conflict); linear gload_lds dest + pre-swizzled global source.
// EPI: 1 = qkv -> bf16 out, phi on cols<1024
//      2 = residual add into Cf
//      3 = +bias, gelu, bf16 out
//      4 = +bias, residual add into Cf
template<int EPI, int K>
__global__ __launch_bounds__(512, 2) void gemm_bt(
    const __bf16* __restrict__ A, const __bf16* __restrict__ BT,
    float* __restrict__ Cf, __bf16* __restrict__ Cb,
    const float* __restrict__ bias, int N, int nbn) {
    constexpr int NK = K / 64;
    __shared__ __align__(16) __bf16 Ab[2][2][256 * 32];
    __shared__ __align__(16) __bf16 Bb[2][2][128 * 32];
    const int t = threadIdx.x;       // 0..511
    const int lane = t & 63;
    const int wave = t >> 6;         // 0..7
    const int wr = wave >> 1;        // 0..3 (M quarters of 64)
    const int wc = wave & 1;         // 0..1 (N halves of 64)
    const int nblk = gridDim.x;
    const int q = nblk >> 3, r = nblk & 7;
    const int xcd = blockIdx.x & 7, loc = blockIdx.x >> 3;
    const int swz = (xcd < r ? xcd * (q + 1) : r * (q + 1) + (xcd - r) * q) + loc;
    const int m0 = (swz / nbn) * 256, n0 = (swz % nbn) * 128;
    const int fr = lane & 15, fc = lane >> 4;

    // staging setup: A khalf = 256x32 = 1024 slots (2/thread); B = 512 (1/thread)
    const __bf16* gA[2];
    int lA[2];
    #pragma unroll
    for (int jj = 0; jj < 2; jj++) {
        int slot = t + 512 * jj;
        int row = slot >> 2, cp = slot & 3;
        int sc = cp ^ ((row >> 1) & 3);
        gA[jj] = A + (size_t)(m0 + row) * K + sc * 8;
        lA[jj] = slot * 8;
    }
    const __bf16* gB;
    int lB;
    {
        int row = t >> 2, cp = t & 3;
        int sc = cp ^ ((row >> 1) & 3);
        gB = BT + (size_t)(n0 + row) * K + sc * 8;
        lB = t * 8;
    }

    auto stageA = [&](int kt, int half, int buf) {
        int koff = kt * 64 + half * 32;
        GLOAD16(gA[0] + koff, &Ab[buf][half][lA[0]]);
        GLOAD16(gA[1] + koff, &Ab[buf][half][lA[1]]);
    };
    auto stageB = [&](int kt, int half, int buf) {
        int koff = kt * 64 + half * 32;
        GLOAD16(gB + koff, &Bb[buf][half][lB]);
    };
    auto rdA = [&](int buf, int kk, int mi) -> bf16x8 {
        int row = wr * 64 + mi * 16 + fr;
        return *(const bf16x8*)&Ab[buf][kk][row * 32 + ((fc ^ ((row >> 1) & 3)) << 3)];
    };
    auto rdB = [&](int buf, int kk, int n) -> bf16x8 {
        int row = wc * 64 + n * 16 + fr;
        return *(const bf16x8*)&Bb[buf][kk][row * 32 + ((fc ^ ((row >> 1) & 3)) << 3)];
    };

    f32x4 acc[4][4];
    #pragma unroll
    for (int m = 0; m < 4; m++)
        #pragma unroll
        for (int n = 0; n < 4; n++)
            acc[m][n] = (f32x4){0.f, 0.f, 0.f, 0.f};

    // prologue: stage ktile 0 (queue: [A0lo2, B0lo1, A0hi2, B0hi1])
    stageA(0, 0, 0); stageB(0, 0, 0); stageA(0, 1, 0); stageB(0, 1, 0);
    asm volatile("s_waitcnt vmcnt(3)" ::: "memory");   // k-lo resident, k-hi in flight
    __builtin_amdgcn_s_barrier();

    for (int j = 0; j < NK; ++j) {
        const int cur = j & 1, nxt = cur ^ 1;
        const bool pf = (j + 1 < NK);
        bf16x8 bfr[4], af0, af1;
        // ---- ph0: k-lo, mi 0-1 ----
        #pragma unroll
        for (int n = 0; n < 4; n++) bfr[n] = rdB(cur, 0, n);
        af0 = rdA(cur, 0, 0); af1 = rdA(cur, 0, 1);
        if (pf) stageA(j + 1, 0, nxt);
        __builtin_amdgcn_s_barrier();
        asm volatile("s_waitcnt lgkmcnt(0)" ::: "memory");
        __builtin_amdgcn_s_setprio(1);
        #pragma unroll
        for (int n = 0; n < 4; n++) {
            acc[0][n] = __builtin_amdgcn_mfma_f32_16x16x32_bf16(af0, bfr[n], acc[0][n], 0, 0, 0);
            acc[1][n] = __builtin_amdgcn_mfma_f32_16x16x32_bf16(af1, bfr[n], acc[1][n], 0, 0, 0);
        }
        __builtin_amdgcn_s_setprio(0);
        __builtin_amdgcn_s_barrier();
        // ---- ph1: k-lo, mi 2-3 ----
        af0 = rdA(cur, 0, 2); af1 = rdA(cur, 0, 3);
        if (pf) {
            stageB(j + 1, 0, nxt);
            asm volatile("s_waitcnt vmcnt(3)" ::: "memory");   // this ktile's k-hi landed
        } else {
            asm volatile("s_waitcnt vmcnt(0)" ::: "memory");
        }
        __builtin_amdgcn_s_barrier();
        asm volatile("s_waitcnt lgkmcnt(0)" ::: "memory");
        __builtin_amdgcn_s_setprio(1);
        #pragma unroll
        for (int n = 0; n < 4; n++) {
            acc[2][n] = __builtin_amdgcn_mfma_f32_16x16x32_bf16(af0, bfr[n], acc[2][n], 0, 0, 0);
            acc[3][n] = __builtin_amdgcn_mfma_f32_16x16x32_bf16(af1, bfr[n], acc[3][n], 0, 0, 0);
        }
        __builtin_amdgcn_s_setprio(0);
        __builtin_amdgcn_s_barrier();
        // ---- ph2: k-hi, mi 0-1 ----
        #pragma unroll
        for (int n = 0; n < 4; n++) bfr[n] = rdB(cur, 1, n);
        af0 = rdA(cur, 1, 0); af1 = rdA(cur, 1, 1);
        if (pf) stageA(j + 1, 1, nxt);
        __builtin_amdgcn_s_barrier();
        asm volatile("s_waitcnt lgkmcnt(0)" ::: "memory");
        __builtin_amdgcn_s_setprio(1);
        #pragma unroll
        for (int n = 0; n < 4; n++) {
            acc[0][n] = __builtin_amdgcn_mfma_f32_16x16x32_bf16(af0, bfr[n], acc[0][n], 0, 0, 0);
            acc[1][n] = __builtin_amdgcn_mfma_f32_16x16x32_bf16(af1, bfr[n], acc[1][n], 0, 0, 0);
        }
        __builtin_amdgcn_s_setprio(0);
        __builtin_amdgcn_s_barrier();
        // ---- ph3: k-hi, mi 2-3 ----
        af0 = rdA(cur, 1, 2); af1 = rdA(cur, 1, 3);
        if (pf) {
            stageB(j + 1, 1, nxt);
            asm volatile("s_waitcnt vmcnt(3)" ::: "memory");   // next ktile's k-lo landed
        }
        __builtin_amdgcn_s_barrier();
        asm volatile("s_waitcnt lgkmcnt(0)" ::: "memory");
        __builtin_amdgcn_s_setprio(1);
        #pragma unroll
        for (int n = 0; n < 4; n++) {
            acc[2][n] = __builtin_amdgcn_mfma_f32_16x16x32_bf16(af0, bfr[n], acc[2][n], 0, 0, 0);
            acc[3][n] = __builtin_amdgcn_mfma_f32_16x16x32_bf16(af1, bfr[n], acc[3][n], 0, 0, 0);
        }
        __builtin_amdgcn_s_setprio(0);
        __builtin_amdgcn_s_barrier();
    }

    const int cr = (lane >> 4) * 4;
    const int cc = lane & 15;
    #pragma unroll
    for (int m = 0; m < 4; m++) {
        #pragma unroll
        for (int n = 0; n < 4; n++) {
            #pragma unroll
            for (int r2 = 0; r2 < 4; r2++) {
                int grow = m0 + wr * 64 + m * 16 + cr + r2;
                int gcol = n0 + wc * 64 + n * 16 + cc;
                size_t idx = (size_t)grow * N + gcol;
                float val = acc[m][n][r2];
                if (EPI == 1) {
                    if (gcol < 1024) val = fmaxf(val, 0.f) + 1e-3f;
                    Cb[idx] = (__bf16)val;
                } else if (EPI == 2) {
                    Cf[idx] += val;
                } else if (EPI == 3) {
                    val += bias[gcol];
                    Cb[idx] = (__bf16)gelu_tanh(val);
                } else if (EPI == 4) {
                    Cf[idx] += val + bias[gcol];
                } else {
                    Cf[idx] = val;
                }
            }
        }
    }
}

// ---------------- kv partial: per (b,h,chunk of 64 rows) 64x64 + pksum ----------------
__global__ __launch_bounds__(256) void kv_partial(const __bf16* __restrict__ qkvb,
                                                  float* __restrict__ part) {
    int bh = blockIdx.x;           // 32
    int chunk = blockIdx.y;        // 64 chunks of 64 rows
    int b = bh >> 3, hh = bh & 7;
    int t = threadIdx.x;
    int f = t & 63, eg = t >> 6;   // e-base = eg*16
    size_t base = ((size_t)b * SEQ + (size_t)chunk * 64) * 1536;
    const __bf16* kcol = qkvb + base + 512 + hh * 64 + f;
    const __bf16* vrow = qkvb + base + 1024 + hh * 64 + eg * 16;
    float psum = 0.f;
    f32x4 a0 = {0.f,0.f,0.f,0.f}, a1 = a0, a2 = a0, a3 = a0;
    for (int s = 0; s < 64; s++) {
        size_t o = (size_t)s * 1536;
        float pk = (float)kcol[o];
        psum += pk;
        bf16x8 w0 = *(const bf16x8*)(vrow + o);
        bf16x8 w1 = *(const bf16x8*)(vrow + o + 8);
        #pragma unroll
        for (int j = 0; j < 4; j++) {
            a0[j] += (float)w0[j]     * pk;
            a1[j] += (float)w0[4 + j] * pk;
            a2[j] += (float)w1[j]     * pk;
            a3[j] += (float)w1[4 + j] * pk;
        }
    }
    float* dst = part + ((size_t)chunk * 32 + bh) * 4160 + (size_t)f * 65 + eg * 16;
    #pragma unroll
    for (int j = 0; j < 4; j++) { dst[j] = a0[j]; dst[4+j] = a1[j]; dst[8+j] = a2[j]; dst[12+j] = a3[j]; }
    if (eg == 0) dst[64] = psum;   // pksum slot
}

__global__ void kv_reduce(const float* __restrict__ part, float* __restrict__ kvfin) {
    int i = blockIdx.x * 256 + threadIdx.x;
    if (i >= 32 * 4160) return;
    float s = 0.f;
    #pragma unroll 8
    for (int c = 0; c < 64; c++) s += part[(size_t)c * (32 * 4160) + i];
    kvfin[i] = s;
}

// ---------------- num / den / divide -> attn (bf16) ----------------
__global__ __launch_bounds__(256) void num_attn(const __bf16* __restrict__ qkvb,
                                                const float* __restrict__ kvfin,
                                                __bf16* __restrict__ attn) {
    __shared__ float kvs[64][68];
    __shared__ float ps[64];
    int bh = blockIdx.x, chunk = blockIdx.y;   // 32 x 32
    int b = bh >> 3, hh = bh & 7;
    const float* src = kvfin + (size_t)bh * 4160;
    for (int i = threadIdx.x; i < 4160; i += 256) {
        int f = i / 65, e = i - f * 65;
        if (e < 64) kvs[f][e] = src[i]; else ps[f] = src[i];
    }
    __syncthreads();
    int t = threadIdx.x;
    int r = t >> 1, e0 = (t & 1) * 32;
    size_t row = (size_t)b * SEQ + (size_t)chunk * 128 + r;
    const __bf16* pqr = qkvb + row * 1536 + hh * 64;
    float pq[64];
    #pragma unroll
    for (int j = 0; j < 8; j++) {
        bf16x8 v = *(const bf16x8*)(pqr + 8 * j);
        #pragma unroll
        for (int k = 0; k < 8; k++) pq[8 * j + k] = (float)v[k];
    }
    float den = 0.f;
    #pragma unroll
    for (int f = 0; f < 64; f++) den += pq[f] * ps[f];
    f32x4 acc[8];
    #pragma unroll
    for (int j = 0; j < 8; j++) acc[j] = (f32x4){0.f,0.f,0.f,0.f};
    for (int f = 0; f < 64; f++) {
        float p = pq[f];
        #pragma unroll
        for (int j = 0; j < 8; j++) acc[j] += *(const f32x4*)(&kvs[f][e0 + 4 * j]) * p;
    }
    float rd = 1.f / den;
    __bf16* op = attn + row * 512 + hh * 64 + e0;
    #pragma unroll
    for (int j2 = 0; j2 < 4; j2++) {
        bf16x8 ov;
        #pragma unroll
        for (int k = 0; k < 8; k++) ov[k] = (__bf16)(acc[j2 * 2 + k / 4][k % 4] * rd);
        *(bf16x8*)(op + j2 * 8) = ov;
    }
}

extern "C" void kernel_launch(void* const* d_in, const int* in_sizes, int n_in,
                              void* d_out, int out_size, void* d_ws, size_t ws_size,
                              hipStream_t stream) {
    const int*   tokens = (const int*)d_in[0];
    const float* embed  = (const float*)d_in[1];
    const float* Wq     = (const float*)d_in[2];
    const float* Wk     = (const float*)d_in[3];
    const float* Wv     = (const float*)d_in[4];
    const float* Wo     = (const float*)d_in[5];
    const float* ln1_s  = (const float*)d_in[6];
    const float* ln1_b  = (const float*)d_in[7];
    const float* W1     = (const float*)d_in[8];
    const float* b1     = (const float*)d_in[9];
    const float* W2     = (const float*)d_in[10];
    const float* b2     = (const float*)d_in[11];
    const float* ln2_s  = (const float*)d_in[12];
    const float* ln2_b  = (const float*)d_in[13];
    const float* lnf_s  = (const float*)d_in[14];
    const float* lnf_b  = (const float*)d_in[15];
    float* out = (float*)d_out;

    float* ws = (float*)d_ws;
    size_t off = 0;
    float* pos = ws;               off += 2097152;            // 4096*512 f32
    float* x   = ws + off;         off += 8388608;            // 16384*512 f32
    __bf16* h    = (__bf16*)(ws + off); off += 4194304;       // 16384*512 bf16
    __bf16* attn = (__bf16*)(ws + off); off += 4194304;       // 16384*512 bf16
    __bf16* qkvb = (__bf16*)(ws + off);                       // 16384*1536 bf16
    __bf16* hid  = (__bf16*)(ws + off); off += 16777216;      // 16384*2048 bf16 (union, serialized)
    float* kvpart = ws + off;      off += 64 * 32 * 4160;     // partials (64 chunks)
    float* kvfin  = ws + off;      off += 32 * 4160;
    __bf16* wbuf  = (__bf16*)(ws + off);                      // 6 * 3145728 bf16

    pos_kernel<<<4096, 256, 0, stream>>>(pos);
    transpose_bf16<<<dim3(16, 16, 6), dim3(32, 8), 0, stream>>>(Wq, wbuf,          512, 512,  262144, 3145728);
    transpose_bf16<<<dim3(16, 16, 6), dim3(32, 8), 0, stream>>>(Wk, wbuf + 262144, 512, 512,  262144, 3145728);
    transpose_bf16<<<dim3(16, 16, 6), dim3(32, 8), 0, stream>>>(Wv, wbuf + 524288, 512, 512,  262144, 3145728);
    transpose_bf16<<<dim3(16, 16, 6), dim3(32, 8), 0, stream>>>(Wo, wbuf + 786432, 512, 512,  262144, 3145728);
    transpose_bf16<<<dim3(64, 16, 6), dim3(32, 8), 0, stream>>>(W1, wbuf + 1048576, 512, 2048, 1048576, 3145728);
    transpose_bf16<<<dim3(16, 64, 6), dim3(32, 8), 0, stream>>>(W2, wbuf + 2097152, 2048, 512, 1048576, 3145728);
    embed_kernel<<<16384, 128, 0, stream>>>(tokens, embed, pos, x);

    for (int l = 0; l < 6; l++) {
        const __bf16* wl = wbuf + (size_t)l * 3145728;
        ln_kernel<1><<<4096, 256, 0, stream>>>(x, ln1_s + l * 512, ln1_b + l * 512, h, nullptr);
        gemm_bt<1, 512><<<768, 512, 0, stream>>>(h, wl, nullptr, qkvb, nullptr, 1536, 12);
        kv_partial<<<dim3(32, 64), 256, 0, stream>>>(qkvb, kvpart);
        kv_reduce<<<520, 256, 0, stream>>>(kvpart, kvfin);
        num_attn<<<dim3(32, 32), 256, 0, stream>>>(qkvb, kvfin, attn);
        gemm_bt<2, 512><<<256, 512, 0, stream>>>(attn, wl + 786432, x, nullptr, nullptr, 512, 4);
        ln_kernel<1><<<4096, 256, 0, stream>>>(x, ln2_s + l * 512, ln2_b + l * 512, h, nullptr);
        gemm_bt<3, 512><<<1024, 512, 0, stream>>>(h, wl + 1048576, nullptr, hid, b1 + (size_t)l * 2048, 2048, 16);
        gemm_bt<4, 2048><<<256, 512, 0, stream>>>(hid, wl + 2097152, x, nullptr, b2 + (size_t)l * 512, 512, 4);
    }
    ln_kernel<0><<<4096, 256, 0, stream>>>(x, lnf_s, lnf_b, nullptr, out);
}